// Round 15
// baseline (261.831 us; speedup 1.0000x reference)
//
#include <hip/hip_runtime.h>

#define KS 1.8033688011112042f  // log2(e)/0.8
#define ZSH 8.0f                // constant exponent shift: E *= 2^-8 (cancels in mu)
#define NTOK 8192
#define VV 8192
#define CHB 26624               // f16 chunk: W 16K + C 8K + BB 1K + BT 1K
#define WS_CC2B 851968
#define WS_VQA  884736          // (-2C) bf16 hi/lo frags, 32 x 32768 -> ws 1933312 B

typedef float f4 __attribute__((ext_vector_type(4)));
typedef short s8v __attribute__((ext_vector_type(8)));
typedef _Float16 h8v __attribute__((ext_vector_type(8)));
typedef __fp16 fp16v2 __attribute__((ext_vector_type(2)));  // builtin's return type
typedef unsigned int u32;
#define AS1 __attribute__((address_space(1)))
#define AS3 __attribute__((address_space(3)))

// RNE float->bf16, bit-ops (prep + VQ path)
static __device__ __forceinline__ unsigned short f2bf(float f) {
  u32 u = __float_as_uint(f);
  return (unsigned short)((u + 0x7fffu + ((u >> 16) & 1u)) >> 16);
}
static __device__ __forceinline__ unsigned short f2h(float f) {  // RNE f32->f16
  _Float16 h = (_Float16)f;
  return __builtin_bit_cast(unsigned short, h);
}
// f16 pack via PLAIN CASTS (RNE; used on the cold x-packing path)
static __device__ __forceinline__ u32 pkh(float a, float b) {
  return (u32)f2h(a) | ((u32)f2h(b) << 16);
}
static __device__ __forceinline__ float h2f(float a) {  // RNE f16 of a, as f32
  return (float)(_Float16)a;
}
// official builtin packed RTZ f16 conversion (hot E-packing path)
static __device__ __forceinline__ u32 pkrtz_b(float a, float b) {
  fp16v2 r = __builtin_amdgcn_cvt_pkrtz(a, b);
  return __builtin_bit_cast(u32, r);
}
// bf16 pack for the VQ path (proven since R3)
static __device__ __forceinline__ u32 cvtpk(float a, float b) {
  u32 r;
  asm("v_cvt_pk_bf16_f32 %0, %1, %2" : "=v"(r) : "v"(a), "v"(b));
  return r;
}
static __device__ __forceinline__ float lof(u32 h) {  // low bf16 as f32
  return __uint_as_float(h << 16);
}
static __device__ __forceinline__ float hif(u32 h) {  // high bf16 as f32
  return __uint_as_float(h & 0xffff0000u);
}

// ws layout (f16 flow path): 32 chunks x 26624 B:
//   [0,16384)     Wf16: 16 subtiles x 64 lanes x 8 f16 (A of mfma1, W*KS, RNE)
//   [16384,24576) Cf16: 8 PAIRS x 64 lanes x 8 f16 (A of mfma2, K=32 pairing)
//   [24576,25600) BB fp32[256] (bm*KS - 8)   [25600,26624) BT fp32[256]
// CC2 fp32[8192] at WS_CC2B; VQA ((-2C) bf16 hi/lo, mfma1-A layout) at WS_VQA.
__global__ __launch_bounds__(64) void prep_kernel(
    const float* __restrict__ cb, const float* __restrict__ Wm,
    const float* __restrict__ bm, const float* __restrict__ tp,
    char* __restrict__ ws) {
  const int ct = blockIdx.x;  // subtile 0..511 (16 codes)
  const int l = threadIdx.x;
  const int g = l >> 4, q = l & 15;
  const int c = ct >> 4, p = ct & 15;
  const int s = p >> 1, par = p & 1;
  char* chunk = ws + (size_t)c * CHB;
  {  // W fragment (A of mfma1): row=code=ct*16+q, k=g*8+j, d=k&15, f16 RNE
    const int code = ct * 16 + q;
    unsigned short wh[8];
#pragma unroll
    for (int j = 0; j < 8; j++) {
      int d = (g * 8 + j) & 15;
      wh[j] = f2h(Wm[d * VV + code] * KS);
    }
    uint4 hv;
    hv.x = (u32)wh[0] | ((u32)wh[1] << 16); hv.y = (u32)wh[2] | ((u32)wh[3] << 16);
    hv.z = (u32)wh[4] | ((u32)wh[5] << 16); hv.w = (u32)wh[6] | ((u32)wh[7] << 16);
    *(uint4*)(chunk + p * 1024 + l * 16) = hv;
  }
  {  // VQ A-fragment: (-2*C) bf16 hi/lo in mfma1-A layout (unchanged, proven)
    const int code = ct * 16 + q;
    unsigned short vh[8], vo[8];
#pragma unroll
    for (int j = 0; j < 8; j++) {
      int d = (g * 8 + j) & 15;
      float v = -2.0f * cb[code * 16 + d];
      unsigned short h = f2bf(v);
      vh[j] = h;
      vo[j] = f2bf(v - __uint_as_float((u32)h << 16));
    }
    uint4 hv, lv;
    hv.x = (u32)vh[0] | ((u32)vh[1] << 16); hv.y = (u32)vh[2] | ((u32)vh[3] << 16);
    hv.z = (u32)vh[4] | ((u32)vh[5] << 16); hv.w = (u32)vh[6] | ((u32)vh[7] << 16);
    lv.x = (u32)vo[0] | ((u32)vo[1] << 16); lv.y = (u32)vo[2] | ((u32)vo[3] << 16);
    lv.z = (u32)vo[4] | ((u32)vo[5] << 16); lv.w = (u32)vo[6] | ((u32)vo[7] << 16);
    char* vq = ws + WS_VQA + (size_t)c * 32768;
    *(uint4*)(vq + p * 1024 + l * 16) = hv;
    *(uint4*)(vq + 16384 + p * 1024 + l * 16) = lv;
  }
  {  // C pair-fragment (A of mfma2), f16 RNE: elems par*4+{0..3} of pair s
    unsigned short ch[4];
#pragma unroll
    for (int j = 0; j < 4; j++) {
      int code = ct * 16 + g * 4 + j;
      ch[j] = f2h(cb[code * 16 + q]);
    }
    uint2 hv = make_uint2((u32)ch[0] | ((u32)ch[1] << 16),
                          (u32)ch[2] | ((u32)ch[3] << 16));
    *(uint2*)(chunk + 16384 + s * 1024 + l * 16 + par * 8) = hv;
  }
  if (l < 16) {
    const int code = ct * 16 + l;
    *(float*)(chunk + 24576 + p * 64 + l * 4) = bm[code] * KS - ZSH;
    *(float*)(chunk + 25600 + p * 64 + l * 4) = tp[code] * KS;
    float ss = 0.f;
#pragma unroll
    for (int d = 0; d < 16; d++) { float v = cb[code * 16 + d]; ss = fmaf(v, v, ss); }
    *(float*)(ws + WS_CC2B + code * 4) = ss;
  }
}

// R15 = R14 + 3-buffer 2-ahead chunk pipeline. R14's 20% idle = correlated
// lockstep vmcnt stalls (4 waves/SIMD issue LOADF at the same point; compute
// ~200cyc < L2 latency ~300cyc, 1-deep prefetch can't cover). Third named
// buffer set `e` (+12 VGPR, still <=128 at 4 waves/SIMD) decouples: 2 chunks
// in flight. Period-3 rolled loop keeps all buffer refs static (rule #20).
// Everything else identical to R14.
__global__ __launch_bounds__(1024, 4) void flow_kernel(
    const float* __restrict__ x0, const char* __restrict__ ws,
    const float* __restrict__ cb, const int* __restrict__ nsp,
    float* __restrict__ out) {
  __shared__ __align__(16) char smem[141312];
  char* biasL = smem;                       // [32 chunks][2048 B] BB|BT
  float* xT = (float*)(smem + 65536);       // [32][16] base state
  float* xM = (float*)(smem + 67584);       // [32][16] midpoint state
  char* redMp = smem + 69632;               // [16 waves][2 tiles][64] f4 (32 KB)
  float* redL = (float*)(smem + 102400);    // [16][32] lsum partials
  float* redV = (float*)(smem + 104448);    // [16][32] VQ min val
  int* redI = (int*)(smem + 106496);        // [16][32] VQ min idx
  float* zL = (float*)(smem + 108544);      // [32 chunks][256] z table (32 KB)
  const float* CC2 = (const float*)(ws + WS_CC2B);

  const int tid = threadIdx.x;
  const int lane = tid & 63, wave = tid >> 6;  // 16 waves
  const int s = wave & 7, cpar = wave >> 3;    // pair id, chunk parity
  const int s2 = s * 2;
  const int g = lane >> 4, q = lane & 15;
  const int tok0 = blockIdx.x * 32;

  if (tid < 128)
    *(float4*)(xT + tid * 4) = *(const float4*)(x0 + tok0 * 16 + tid * 4);
  // biases -> LDS once (wave-uniform dst base + lane*16: valid global_load_lds)
#pragma unroll
  for (int sw = 0; sw < 4; sw++) {
    const int c = sw * 8 + (tid >> 7);
    const int off = (tid & 127) * 16;
    __builtin_amdgcn_global_load_lds(
        (const AS1 u32*)(ws + (size_t)c * CHB + 24576 + off),
        (AS3 u32*)(biasL + c * 2048 + off), 16, 0, 0);
  }
  __syncthreads();

  const int n_steps = *nsp;
  const float dt = 1.0f / (float)(n_steps - 1);

  // ones A-fragment (f16 1.0 pairs) for the lsum MFMA
  union { u32 u[4]; h8v h; } ONESH;
  ONESH.u[0] = ONESH.u[1] = ONESH.u[2] = ONESH.u[3] = 0x3c003c00u;

  // named triple-buffered fragment registers (NO arrays — rule #20)
  h8v aW0, aW1, aCf;
  h8v bW0, bW1, bCf;
  h8v eW0, eW1, eCf;

// conflict-light ZFILL: lanes write 16-B-contiguous (2 passes of 128 floats)
#define ZFILL(TT) {                                                         \
    const int _c = tid >> 5;                                                \
    const int _t = tid & 31;                                                \
    const char* _bp = biasL + _c * 2048;                                    \
    float4 _b0 = *(const float4*)(_bp + _t * 16);                           \
    float4 _t0 = *(const float4*)(_bp + 1024 + _t * 16);                    \
    float4 _b1 = *(const float4*)(_bp + 512 + _t * 16);                     \
    float4 _t1 = *(const float4*)(_bp + 1536 + _t * 16);                    \
    float4 _za, _zb;                                                        \
    _za.x = fmaf(TT, _t0.x, _b0.x); _za.y = fmaf(TT, _t0.y, _b0.y);         \
    _za.z = fmaf(TT, _t0.z, _b0.z); _za.w = fmaf(TT, _t0.w, _b0.w);         \
    _zb.x = fmaf(TT, _t1.x, _b1.x); _zb.y = fmaf(TT, _t1.y, _b1.y);         \
    _zb.z = fmaf(TT, _t1.z, _b1.z); _zb.w = fmaf(TT, _t1.w, _b1.w);         \
    *(float4*)(zL + _c * 256 + _t * 4) = _za;                               \
    *(float4*)(zL + _c * 256 + 128 + _t * 4) = _zb;                         \
  }

#define LOADF(P, c) {                                                       \
    const char* _p = ws + (size_t)(c) * CHB;                                \
    P##W0 = *(const h8v*)(_p + s2 * 1024 + lane * 16);                      \
    P##W1 = *(const h8v*)(_p + (s2 + 1) * 1024 + lane * 16);                \
    P##Cf = *(const h8v*)(_p + 16384 + s * 1024 + lane * 16);               \
  }

#define TBODY(W0F, W1F, CFF, BX, MACC, LACC, Z0, Z1) {                      \
    f4 _D0 = {Z0.x, Z0.y, Z0.z, Z0.w};  /* bias (incl -8 shift) as C-in */  \
    _D0 = __builtin_amdgcn_mfma_f32_16x16x32_f16(W0F, BX, _D0, 0, 0, 0);    \
    f4 _D1 = {Z1.x, Z1.y, Z1.z, Z1.w};                                      \
    _D1 = __builtin_amdgcn_mfma_f32_16x16x32_f16(W1F, BX, _D1, 0, 0, 0);    \
    float _e0 = __builtin_amdgcn_exp2f(_D0[0]);                             \
    float _e1 = __builtin_amdgcn_exp2f(_D0[1]);                             \
    float _e2 = __builtin_amdgcn_exp2f(_D0[2]);                             \
    float _e3 = __builtin_amdgcn_exp2f(_D0[3]);                             \
    float _e4 = __builtin_amdgcn_exp2f(_D1[0]);                             \
    float _e5 = __builtin_amdgcn_exp2f(_D1[1]);                             \
    float _e6 = __builtin_amdgcn_exp2f(_D1[2]);                             \
    float _e7 = __builtin_amdgcn_exp2f(_D1[3]);                             \
    union { u32 u[4]; h8v h; } _Eh;                                         \
    _Eh.u[0] = pkrtz_b(_e0, _e1); _Eh.u[1] = pkrtz_b(_e2, _e3);             \
    _Eh.u[2] = pkrtz_b(_e4, _e5); _Eh.u[3] = pkrtz_b(_e6, _e7);             \
    MACC = __builtin_amdgcn_mfma_f32_16x16x32_f16(CFF, _Eh.h, MACC, 0, 0, 0); \
    LACC = __builtin_amdgcn_mfma_f32_16x16x32_f16(ONESH.h, _Eh.h, LACC, 0, 0, 0); \
  }

#define COMPUTE(P, c) {                                                     \
    const float* _zp = zL + (c) * 256 + s2 * 16 + g * 4;                    \
    float4 _z0 = *(const float4*)(_zp);                                     \
    float4 _z1 = *(const float4*)(_zp + 16);                                \
    TBODY(P##W0, P##W1, P##Cf, Bx0.h, macc0, lacc0, _z0, _z1);              \
    TBODY(P##W0, P##W1, P##Cf, Bx1.h, macc1, lacc1, _z0, _z1);              \
  }

  // prologue: z table for phase 0 (tt = 0) + first two chunk prefetches
  ZFILL(0.0f);
  LOADF(a, cpar);
  LOADF(b, cpar + 2);
  __syncthreads();

  for (int step = 0; step < n_steps - 1; step++) {
#pragma unroll 1
    for (int mh = 0; mh < 2; mh++) {
      const float tt = (float)step * dt + (mh ? 0.5f * dt : 0.0f);
      const float* xsrc = mh ? xM : xT;
      // B-frags of mfma1: col=tok=q, k=g*8+j; k<16 -> xh[d=k] (f16 RNE),
      // k>=16 -> xl[d=k-16] (residual vs the same RNE). g covers d=(g&1)*8..+7.
      union { u32 u[4]; h8v h; } Bx0, Bx1;
#pragma unroll
      for (int T = 0; T < 2; T++) {
        const float* xp = xsrc + (T * 16 + q) * 16 + (g & 1) * 8;
        float4 a = *(const float4*)(xp);
        float4 b = *(const float4*)(xp + 4);
        u32 r0, r1, r2, r3;
        if (g < 2) {
          r0 = pkh(a.x, a.y); r1 = pkh(a.z, a.w);
          r2 = pkh(b.x, b.y); r3 = pkh(b.z, b.w);
        } else {
          r0 = pkh(a.x - h2f(a.x), a.y - h2f(a.y));
          r1 = pkh(a.z - h2f(a.z), a.w - h2f(a.w));
          r2 = pkh(b.x - h2f(b.x), b.y - h2f(b.y));
          r3 = pkh(b.z - h2f(b.z), b.w - h2f(b.w));
        }
        if (T == 0) { Bx0.u[0] = r0; Bx0.u[1] = r1; Bx0.u[2] = r2; Bx0.u[3] = r3; }
        else        { Bx1.u[0] = r0; Bx1.u[1] = r1; Bx1.u[2] = r2; Bx1.u[3] = r3; }
      }
      f4 macc0 = {0.f, 0.f, 0.f, 0.f}, macc1 = {0.f, 0.f, 0.f, 0.f};
      f4 lacc0 = {0.f, 0.f, 0.f, 0.f}, lacc1 = {0.f, 0.f, 0.f, 0.f};

      // chunk pipeline: 16 chunks {cpar, cpar+2, ...}, 2 AHEAD (3 buffers).
      // a=chunk0, b=chunk1 preloaded by prologue / previous finalize window.
#pragma unroll 1
      for (int i = 0; i < 5; i++) {
        const int k3 = cpar + 6 * i;     // chunk index of this triple's first
        LOADF(e, k3 + 4);
        COMPUTE(a, k3);
        LOADF(a, k3 + 6);
        COMPUTE(b, k3 + 2);
        if (i < 4) LOADF(b, k3 + 8);
        COMPUTE(e, k3 + 4);
      }
      COMPUTE(a, cpar + 30);             // chunk 15 (loaded at i=4)

      // partials: macc per lane; lsum complete per tok in lacc (any row reg)
      *(f4*)(redMp + ((wave * 2 + 0) * 64 + lane) * 16) = macc0;
      *(f4*)(redMp + ((wave * 2 + 1) * 64 + lane) * 16) = macc1;
      if (lane < 16) {
        redL[wave * 32 + lane] = lacc0[0];
        redL[wave * 32 + 16 + lane] = lacc1[0];
      }
      __syncthreads();
      // prefetch next phase's first two chunks — latency hides under finalize
      LOADF(a, cpar);
      LOADF(b, cpar + 2);
      // z table for the NEXT phase — overlaps the finalize serial window
      const float ttn = (mh == 0) ? (tt + 0.5f * dt) : ((float)(step + 1) * dt);
      ZFILL(ttn);
      if ((wave & 7) == 0) {  // waves 0 (tile0) and 8 (tile1) finalize
        const int T2 = wave >> 3;
        f4 m = {0.f, 0.f, 0.f, 0.f};
        float l2 = 0.f;
#pragma unroll
        for (int w = 0; w < 16; w++) {
          f4 o = *(const f4*)(redMp + ((w * 2 + T2) * 64 + lane) * 16);
          m += o;
          l2 += redL[w * 32 + T2 * 16 + q];
        }
        const float inv = 1.0f / fmaxf(l2, 1e-37f);
        const float inv1 = 1.0f / (1.0f - tt + 1e-10f);
        const float cf = (mh == 0) ? (0.5f * dt * inv1) : (dt * inv1);
        // lane owns (tok=q, d=g*4+j) of its tile: contiguous float4
        float4 xb = *(const float4*)(xT + (T2 * 16 + q) * 16 + g * 4);
        float4 xs = mh ? *(const float4*)(xM + (T2 * 16 + q) * 16 + g * 4) : xb;
        float4 xn;
        xn.x = fmaf(cf, m[0] * inv - xs.x, xb.x);
        xn.y = fmaf(cf, m[1] * inv - xs.y, xb.y);
        xn.z = fmaf(cf, m[2] * inv - xs.z, xb.z);
        xn.w = fmaf(cf, m[3] * inv - xs.w, xb.w);
        *(float4*)((mh ? xT : xM) + (T2 * 16 + q) * 16 + g * 4) = xn;
      }
      __syncthreads();
    }
  }

  // ---- outputs: x_final ----
  if (tid < 128)
    *(float4*)(out + tok0 * 16 + tid * 4) = *(const float4*)(xT + tid * 4);

  // ---- VQ argmin via bf16 MFMA (bit-identical to R10): dist = cc - 2 x.c ----
  union { u32 u[4]; s8v v; } Vx0, Vx1;
#pragma unroll
  for (int T = 0; T < 2; T++) {
    const float* xp = xT + (T * 16 + q) * 16 + (g & 1) * 8;
    float4 a = *(const float4*)(xp);
    float4 b = *(const float4*)(xp + 4);
    u32 h0 = cvtpk(a.x, a.y), h1 = cvtpk(a.z, a.w);
    u32 h2 = cvtpk(b.x, b.y), h3 = cvtpk(b.z, b.w);
    u32 r0, r1, r2, r3;
    if (g < 2) {
      r0 = h0; r1 = h1; r2 = h2; r3 = h3;
    } else {
      r0 = cvtpk(a.x - lof(h0), a.y - hif(h0));
      r1 = cvtpk(a.z - lof(h1), a.w - hif(h1));
      r2 = cvtpk(b.x - lof(h2), b.y - hif(h2));
      r3 = cvtpk(b.z - lof(h3), b.w - hif(h3));
    }
    if (T == 0) { Vx0.u[0] = r0; Vx0.u[1] = r1; Vx0.u[2] = r2; Vx0.u[3] = r3; }
    else        { Vx1.u[0] = r0; Vx1.u[1] = r1; Vx1.u[2] = r2; Vx1.u[3] = r3; }
  }
  float mv0 = 3.402823466e38f, mv1 = 3.402823466e38f;
  int mi0 = 0, mi1 = 0;
  s8v pAh0, pAl0, pAh1, pAl1;
  s8v qAh0, qAl0, qAh1, qAl1;
  float4 pC0, pC1, qC0, qC1;

#define VQLOAD(P, c) {                                                      \
    const char* _a = ws + WS_VQA + (size_t)(c) * 32768;                     \
    P##Ah0 = *(const s8v*)(_a + s2 * 1024 + lane * 16);                     \
    P##Al0 = *(const s8v*)(_a + 16384 + s2 * 1024 + lane * 16);             \
    P##Ah1 = *(const s8v*)(_a + (s2 + 1) * 1024 + lane * 16);               \
    P##Al1 = *(const s8v*)(_a + 16384 + (s2 + 1) * 1024 + lane * 16);       \
    P##C0 = *(const float4*)(CC2 + (c) * 256 + s2 * 16 + (lane >> 4) * 4);  \
    P##C1 = *(const float4*)(CC2 + (c) * 256 + (s2 + 1) * 16 + (lane >> 4) * 4); \
  }

#define VQMIN(MV, MI, DV, IDX) { float _d = (DV); if (_d < MV) { MV = _d; MI = (IDX); } }

#define VQTILE(P, VX, MV, MI, c) {                                          \
    const int _b0 = (c) * 256 + s2 * 16 + (lane >> 4) * 4;                  \
    const int _b1 = _b0 + 16;                                               \
    f4 _E0 = {P##C0.x, P##C0.y, P##C0.z, P##C0.w};                          \
    _E0 = __builtin_amdgcn_mfma_f32_16x16x32_bf16(P##Ah0, VX, _E0, 0, 0, 0);\
    _E0 = __builtin_amdgcn_mfma_f32_16x16x32_bf16(P##Al0, VX, _E0, 0, 0, 0);\
    f4 _E1 = {P##C1.x, P##C1.y, P##C1.z, P##C1.w};                          \
    _E1 = __builtin_amdgcn_mfma_f32_16x16x32_bf16(P##Ah1, VX, _E1, 0, 0, 0);\
    _E1 = __builtin_amdgcn_mfma_f32_16x16x32_bf16(P##Al1, VX, _E1, 0, 0, 0);\
    VQMIN(MV, MI, _E0[0], _b0 + 0); VQMIN(MV, MI, _E0[1], _b0 + 1);         \
    VQMIN(MV, MI, _E0[2], _b0 + 2); VQMIN(MV, MI, _E0[3], _b0 + 3);         \
    VQMIN(MV, MI, _E1[0], _b1 + 0); VQMIN(MV, MI, _E1[1], _b1 + 1);         \
    VQMIN(MV, MI, _E1[2], _b1 + 2); VQMIN(MV, MI, _E1[3], _b1 + 3);         \
  }

#define VQSTEP(P, c) { VQTILE(P, Vx0.v, mv0, mi0, c) VQTILE(P, Vx1.v, mv1, mi1, c) }

  VQLOAD(p, cpar);
#pragma unroll 1
  for (int i = 0; i < 16; i += 2) {
    VQLOAD(q, cpar + 2 * (i + 1));
    VQSTEP(p, cpar + 2 * i);
    if (i + 2 < 16) VQLOAD(p, cpar + 2 * (i + 2));
    VQSTEP(q, cpar + 2 * (i + 1));
  }
  // cross-lane argmin over the 4 lanes sharing tok = lane&15 (rows)
#pragma unroll
  for (int m = 16; m < 64; m <<= 1) {
    float ov0 = __shfl_xor(mv0, m, 64); int oi0 = __shfl_xor(mi0, m, 64);
    if (ov0 < mv0 || (ov0 == mv0 && oi0 < mi0)) { mv0 = ov0; mi0 = oi0; }
    float ov1 = __shfl_xor(mv1, m, 64); int oi1 = __shfl_xor(mi1, m, 64);
    if (ov1 < mv1 || (ov1 == mv1 && oi1 < mi1)) { mv1 = ov1; mi1 = oi1; }
  }
  if (lane < 16) {
    redV[wave * 32 + lane] = mv0; redI[wave * 32 + lane] = mi0;
    redV[wave * 32 + 16 + lane] = mv1; redI[wave * 32 + 16 + lane] = mi1;
  }
  __syncthreads();
  if (tid < 32) {
    float bv = redV[tid];
    int bi = redI[tid];
#pragma unroll
    for (int w = 1; w < 16; w++) {
      float ov = redV[w * 32 + tid];
      int oi = redI[w * 32 + tid];
      if (ov < bv || (ov == bv && oi < bi)) { bv = ov; bi = oi; }
    }
    out[NTOK * 16 + tok0 + tid] = (float)bi;
  }
}

extern "C" void kernel_launch(void* const* d_in, const int* in_sizes, int n_in,
                              void* d_out, int out_size, void* d_ws, size_t ws_size,
                              hipStream_t stream) {
  const float* x0 = (const float*)d_in[0];
  const float* cb = (const float*)d_in[1];
  const float* Wm = (const float*)d_in[2];
  const float* bm = (const float*)d_in[3];
  const float* tp = (const float*)d_in[4];
  const int* ns = (const int*)d_in[5];
  char* ws = (char*)d_ws;  // needs 1933312 B
  float* out = (float*)d_out;

  prep_kernel<<<512, 64, 0, stream>>>(cb, Wm, bm, tp, ws);
  flow_kernel<<<256, 1024, 0, stream>>>(x0, ws, cb, ns, out);
}

// Round 16
// 240.498 us; speedup vs baseline: 1.0887x; 1.0887x over previous
//
#include <hip/hip_runtime.h>

#define KS 1.8033688011112042f  // log2(e)/0.8
#define ZSH 8.0f                // constant exponent shift: E *= 2^-8 (cancels in mu)
#define NTOK 8192
#define VV 8192
#define CHB 26624               // f16 chunk: W 16K + C 8K + BB 1K + BT 1K
#define WS_CC2B 851968
#define WS_VQA  884736          // (-2C) bf16 hi/lo frags, 32 x 32768 -> ws 1933312 B
#define XSTR 20                 // padded token stride for xT/xM (bank-conflict fix)

typedef float f4 __attribute__((ext_vector_type(4)));
typedef short s8v __attribute__((ext_vector_type(8)));
typedef _Float16 h8v __attribute__((ext_vector_type(8)));
typedef __fp16 fp16v2 __attribute__((ext_vector_type(2)));  // builtin's return type
typedef unsigned int u32;
#define AS1 __attribute__((address_space(1)))
#define AS3 __attribute__((address_space(3)))

// RNE float->bf16, bit-ops (prep + VQ path)
static __device__ __forceinline__ unsigned short f2bf(float f) {
  u32 u = __float_as_uint(f);
  return (unsigned short)((u + 0x7fffu + ((u >> 16) & 1u)) >> 16);
}
static __device__ __forceinline__ unsigned short f2h(float f) {  // RNE f32->f16
  _Float16 h = (_Float16)f;
  return __builtin_bit_cast(unsigned short, h);
}
// f16 pack via PLAIN CASTS (RNE; used on the cold x-packing path)
static __device__ __forceinline__ u32 pkh(float a, float b) {
  return (u32)f2h(a) | ((u32)f2h(b) << 16);
}
static __device__ __forceinline__ float h2f(float a) {  // RNE f16 of a, as f32
  return (float)(_Float16)a;
}
// official builtin packed RTZ f16 conversion (hot E-packing path)
static __device__ __forceinline__ u32 pkrtz_b(float a, float b) {
  fp16v2 r = __builtin_amdgcn_cvt_pkrtz(a, b);
  return __builtin_bit_cast(u32, r);
}
// bf16 pack for the VQ path (proven since R3)
static __device__ __forceinline__ u32 cvtpk(float a, float b) {
  u32 r;
  asm("v_cvt_pk_bf16_f32 %0, %1, %2" : "=v"(r) : "v"(a), "v"(b));
  return r;
}
static __device__ __forceinline__ float lof(u32 h) {  // low bf16 as f32
  return __uint_as_float(h << 16);
}
static __device__ __forceinline__ float hif(u32 h) {  // high bf16 as f32
  return __uint_as_float(h & 0xffff0000u);
}

// ws layout (f16 flow path): 32 chunks x 26624 B:
//   [0,16384)     Wf16: 16 subtiles x 64 lanes x 8 f16 (A of mfma1, W*KS, RNE)
//   [16384,24576) Cf16: 8 PAIRS x 64 lanes x 8 f16 (A of mfma2, K=32 pairing)
//   [24576,25600) BB fp32[256] (bm*KS - 8)   [25600,26624) BT fp32[256]
// CC2 fp32[8192] at WS_CC2B; VQA ((-2C) bf16 hi/lo, mfma1-A layout) at WS_VQA.
__global__ __launch_bounds__(64) void prep_kernel(
    const float* __restrict__ cb, const float* __restrict__ Wm,
    const float* __restrict__ bm, const float* __restrict__ tp,
    char* __restrict__ ws) {
  const int ct = blockIdx.x;  // subtile 0..511 (16 codes)
  const int l = threadIdx.x;
  const int g = l >> 4, q = l & 15;
  const int c = ct >> 4, p = ct & 15;
  const int s = p >> 1, par = p & 1;
  char* chunk = ws + (size_t)c * CHB;
  {  // W fragment (A of mfma1): row=code=ct*16+q, k=g*8+j, d=k&15, f16 RNE
    const int code = ct * 16 + q;
    unsigned short wh[8];
#pragma unroll
    for (int j = 0; j < 8; j++) {
      int d = (g * 8 + j) & 15;
      wh[j] = f2h(Wm[d * VV + code] * KS);
    }
    uint4 hv;
    hv.x = (u32)wh[0] | ((u32)wh[1] << 16); hv.y = (u32)wh[2] | ((u32)wh[3] << 16);
    hv.z = (u32)wh[4] | ((u32)wh[5] << 16); hv.w = (u32)wh[6] | ((u32)wh[7] << 16);
    *(uint4*)(chunk + p * 1024 + l * 16) = hv;
  }
  {  // VQ A-fragment: (-2*C) bf16 hi/lo in mfma1-A layout (unchanged, proven)
    const int code = ct * 16 + q;
    unsigned short vh[8], vo[8];
#pragma unroll
    for (int j = 0; j < 8; j++) {
      int d = (g * 8 + j) & 15;
      float v = -2.0f * cb[code * 16 + d];
      unsigned short h = f2bf(v);
      vh[j] = h;
      vo[j] = f2bf(v - __uint_as_float((u32)h << 16));
    }
    uint4 hv, lv;
    hv.x = (u32)vh[0] | ((u32)vh[1] << 16); hv.y = (u32)vh[2] | ((u32)vh[3] << 16);
    hv.z = (u32)vh[4] | ((u32)vh[5] << 16); hv.w = (u32)vh[6] | ((u32)vh[7] << 16);
    lv.x = (u32)vo[0] | ((u32)vo[1] << 16); lv.y = (u32)vo[2] | ((u32)vo[3] << 16);
    lv.z = (u32)vo[4] | ((u32)vo[5] << 16); lv.w = (u32)vo[6] | ((u32)vo[7] << 16);
    char* vq = ws + WS_VQA + (size_t)c * 32768;
    *(uint4*)(vq + p * 1024 + l * 16) = hv;
    *(uint4*)(vq + 16384 + p * 1024 + l * 16) = lv;
  }
  {  // C pair-fragment (A of mfma2), f16 RNE: elems par*4+{0..3} of pair s
    unsigned short ch[4];
#pragma unroll
    for (int j = 0; j < 4; j++) {
      int code = ct * 16 + g * 4 + j;
      ch[j] = f2h(cb[code * 16 + q]);
    }
    uint2 hv = make_uint2((u32)ch[0] | ((u32)ch[1] << 16),
                          (u32)ch[2] | ((u32)ch[3] << 16));
    *(uint2*)(chunk + 16384 + s * 1024 + l * 16 + par * 8) = hv;
  }
  if (l < 16) {
    const int code = ct * 16 + l;
    *(float*)(chunk + 24576 + p * 64 + l * 4) = bm[code] * KS - ZSH;
    *(float*)(chunk + 25600 + p * 64 + l * 4) = tp[code] * KS;
    float ss = 0.f;
#pragma unroll
    for (int d = 0; d < 16; d++) { float v = cb[code * 16 + d]; ss = fmaf(v, v, ss); }
    *(float*)(ws + WS_CC2B + code * 4) = ss;
  }
}

// R16 = R14 revert (R15's 3rd buffer spilled to scratch: VGPR pinned 64,
// WRITE 18->40 MB, neutral-negative) + xT/xM token stride padded 16->20
// floats: Bx/VQ packing read lane q at 64B stride = 8-way bank conflict
// (13.3M conflict cycles); q*20 mod 32 spreads over 8 banks -> 2-way (free).
// Pure layout change; arithmetic bit-identical to R14.
__global__ __launch_bounds__(1024, 4) void flow_kernel(
    const float* __restrict__ x0, const char* __restrict__ ws,
    const float* __restrict__ cb, const int* __restrict__ nsp,
    float* __restrict__ out) {
  __shared__ __align__(16) char smem[142336];
  char* biasL = smem;                       // [32 chunks][2048 B] BB|BT
  float* xT = (float*)(smem + 65536);       // [32][XSTR] base state (2560 B)
  float* xM = (float*)(smem + 68096);       // [32][XSTR] midpoint state
  char* redMp = smem + 70656;               // [16 waves][2 tiles][64] f4 (32 KB)
  float* redL = (float*)(smem + 103424);    // [16][32] lsum partials
  float* redV = (float*)(smem + 105472);    // [16][32] VQ min val
  int* redI = (int*)(smem + 107520);        // [16][32] VQ min idx
  float* zL = (float*)(smem + 109568);      // [32 chunks][256] z table (32 KB)
  const float* CC2 = (const float*)(ws + WS_CC2B);

  const int tid = threadIdx.x;
  const int lane = tid & 63, wave = tid >> 6;  // 16 waves
  const int s = wave & 7, cpar = wave >> 3;    // pair id, chunk parity
  const int s2 = s * 2;
  const int g = lane >> 4, q = lane & 15;
  const int tok0 = blockIdx.x * 32;

  if (tid < 128)
    *(float4*)(xT + (tid >> 2) * XSTR + (tid & 3) * 4) =
        *(const float4*)(x0 + tok0 * 16 + tid * 4);
  // biases -> LDS once (wave-uniform dst base + lane*16: valid global_load_lds)
#pragma unroll
  for (int sw = 0; sw < 4; sw++) {
    const int c = sw * 8 + (tid >> 7);
    const int off = (tid & 127) * 16;
    __builtin_amdgcn_global_load_lds(
        (const AS1 u32*)(ws + (size_t)c * CHB + 24576 + off),
        (AS3 u32*)(biasL + c * 2048 + off), 16, 0, 0);
  }
  __syncthreads();

  const int n_steps = *nsp;
  const float dt = 1.0f / (float)(n_steps - 1);

  // ones A-fragment (f16 1.0 pairs) for the lsum MFMA
  union { u32 u[4]; h8v h; } ONESH;
  ONESH.u[0] = ONESH.u[1] = ONESH.u[2] = ONESH.u[3] = 0x3c003c00u;

  // named double-buffered fragment registers (NO arrays — rule #20)
  h8v aW0, aW1, aCf;
  h8v bW0, bW1, bCf;

// conflict-light ZFILL: lanes write 16-B-contiguous (2 passes of 128 floats)
#define ZFILL(TT) {                                                         \
    const int _c = tid >> 5;                                                \
    const int _t = tid & 31;                                                \
    const char* _bp = biasL + _c * 2048;                                    \
    float4 _b0 = *(const float4*)(_bp + _t * 16);                           \
    float4 _t0 = *(const float4*)(_bp + 1024 + _t * 16);                    \
    float4 _b1 = *(const float4*)(_bp + 512 + _t * 16);                     \
    float4 _t1 = *(const float4*)(_bp + 1536 + _t * 16);                    \
    float4 _za, _zb;                                                        \
    _za.x = fmaf(TT, _t0.x, _b0.x); _za.y = fmaf(TT, _t0.y, _b0.y);         \
    _za.z = fmaf(TT, _t0.z, _b0.z); _za.w = fmaf(TT, _t0.w, _b0.w);         \
    _zb.x = fmaf(TT, _t1.x, _b1.x); _zb.y = fmaf(TT, _t1.y, _b1.y);         \
    _zb.z = fmaf(TT, _t1.z, _b1.z); _zb.w = fmaf(TT, _t1.w, _b1.w);         \
    *(float4*)(zL + _c * 256 + _t * 4) = _za;                               \
    *(float4*)(zL + _c * 256 + 128 + _t * 4) = _zb;                         \
  }

#define LOADF(P, c) {                                                       \
    const char* _p = ws + (size_t)(c) * CHB;                                \
    P##W0 = *(const h8v*)(_p + s2 * 1024 + lane * 16);                      \
    P##W1 = *(const h8v*)(_p + (s2 + 1) * 1024 + lane * 16);                \
    P##Cf = *(const h8v*)(_p + 16384 + s * 1024 + lane * 16);               \
  }

#define TBODY(W0F, W1F, CFF, BX, MACC, LACC, Z0, Z1) {                      \
    f4 _D0 = {Z0.x, Z0.y, Z0.z, Z0.w};  /* bias (incl -8 shift) as C-in */  \
    _D0 = __builtin_amdgcn_mfma_f32_16x16x32_f16(W0F, BX, _D0, 0, 0, 0);    \
    f4 _D1 = {Z1.x, Z1.y, Z1.z, Z1.w};                                      \
    _D1 = __builtin_amdgcn_mfma_f32_16x16x32_f16(W1F, BX, _D1, 0, 0, 0);    \
    float _e0 = __builtin_amdgcn_exp2f(_D0[0]);                             \
    float _e1 = __builtin_amdgcn_exp2f(_D0[1]);                             \
    float _e2 = __builtin_amdgcn_exp2f(_D0[2]);                             \
    float _e3 = __builtin_amdgcn_exp2f(_D0[3]);                             \
    float _e4 = __builtin_amdgcn_exp2f(_D1[0]);                             \
    float _e5 = __builtin_amdgcn_exp2f(_D1[1]);                             \
    float _e6 = __builtin_amdgcn_exp2f(_D1[2]);                             \
    float _e7 = __builtin_amdgcn_exp2f(_D1[3]);                             \
    union { u32 u[4]; h8v h; } _Eh;                                         \
    _Eh.u[0] = pkrtz_b(_e0, _e1); _Eh.u[1] = pkrtz_b(_e2, _e3);             \
    _Eh.u[2] = pkrtz_b(_e4, _e5); _Eh.u[3] = pkrtz_b(_e6, _e7);             \
    MACC = __builtin_amdgcn_mfma_f32_16x16x32_f16(CFF, _Eh.h, MACC, 0, 0, 0); \
    LACC = __builtin_amdgcn_mfma_f32_16x16x32_f16(ONESH.h, _Eh.h, LACC, 0, 0, 0); \
  }

#define COMPUTE(P, c) {                                                     \
    const float* _zp = zL + (c) * 256 + s2 * 16 + g * 4;                    \
    float4 _z0 = *(const float4*)(_zp);                                     \
    float4 _z1 = *(const float4*)(_zp + 16);                                \
    TBODY(P##W0, P##W1, P##Cf, Bx0.h, macc0, lacc0, _z0, _z1);              \
    TBODY(P##W0, P##W1, P##Cf, Bx1.h, macc1, lacc1, _z0, _z1);              \
  }

  // prologue: z table for phase 0 (tt = 0) + first chunk prefetch
  ZFILL(0.0f);
  LOADF(a, cpar);
  __syncthreads();

  for (int step = 0; step < n_steps - 1; step++) {
#pragma unroll 1
    for (int mh = 0; mh < 2; mh++) {
      const float tt = (float)step * dt + (mh ? 0.5f * dt : 0.0f);
      const float* xsrc = mh ? xM : xT;
      // B-frags of mfma1: col=tok=q, k=g*8+j; k<16 -> xh[d=k] (f16 RNE),
      // k>=16 -> xl[d=k-16] (residual vs the same RNE). g covers d=(g&1)*8..+7.
      union { u32 u[4]; h8v h; } Bx0, Bx1;
#pragma unroll
      for (int T = 0; T < 2; T++) {
        const float* xp = xsrc + (T * 16 + q) * XSTR + (g & 1) * 8;
        float4 a = *(const float4*)(xp);
        float4 b = *(const float4*)(xp + 4);
        u32 r0, r1, r2, r3;
        if (g < 2) {
          r0 = pkh(a.x, a.y); r1 = pkh(a.z, a.w);
          r2 = pkh(b.x, b.y); r3 = pkh(b.z, b.w);
        } else {
          r0 = pkh(a.x - h2f(a.x), a.y - h2f(a.y));
          r1 = pkh(a.z - h2f(a.z), a.w - h2f(a.w));
          r2 = pkh(b.x - h2f(b.x), b.y - h2f(b.y));
          r3 = pkh(b.z - h2f(b.z), b.w - h2f(b.w));
        }
        if (T == 0) { Bx0.u[0] = r0; Bx0.u[1] = r1; Bx0.u[2] = r2; Bx0.u[3] = r3; }
        else        { Bx1.u[0] = r0; Bx1.u[1] = r1; Bx1.u[2] = r2; Bx1.u[3] = r3; }
      }
      f4 macc0 = {0.f, 0.f, 0.f, 0.f}, macc1 = {0.f, 0.f, 0.f, 0.f};
      f4 lacc0 = {0.f, 0.f, 0.f, 0.f}, lacc1 = {0.f, 0.f, 0.f, 0.f};

      // chunk pipeline: this wave's 16 chunks {cpar, cpar+2, ...}, 1 ahead
      // (a-regs preloaded with chunk cpar by prologue / previous phase tail)
#pragma unroll 1
      for (int j = 0; j < 16; j += 2) {
        LOADF(b, cpar + 2 * (j + 1));
        COMPUTE(a, cpar + 2 * j);
        if (j + 2 < 16) LOADF(a, cpar + 2 * (j + 2));
        COMPUTE(b, cpar + 2 * (j + 1));
      }

      // partials: macc per lane; lsum complete per tok in lacc (any row reg)
      *(f4*)(redMp + ((wave * 2 + 0) * 64 + lane) * 16) = macc0;
      *(f4*)(redMp + ((wave * 2 + 1) * 64 + lane) * 16) = macc1;
      if (lane < 16) {
        redL[wave * 32 + lane] = lacc0[0];
        redL[wave * 32 + 16 + lane] = lacc1[0];
      }
      __syncthreads();
      // prefetch next phase's first chunk — L2 latency hides under finalize
      LOADF(a, cpar);
      // z table for the NEXT phase — overlaps the finalize serial window
      const float ttn = (mh == 0) ? (tt + 0.5f * dt) : ((float)(step + 1) * dt);
      ZFILL(ttn);
      if ((wave & 7) == 0) {  // waves 0 (tile0) and 8 (tile1) finalize
        const int T2 = wave >> 3;
        f4 m = {0.f, 0.f, 0.f, 0.f};
        float l2 = 0.f;
#pragma unroll
        for (int w = 0; w < 16; w++) {
          f4 o = *(const f4*)(redMp + ((w * 2 + T2) * 64 + lane) * 16);
          m += o;
          l2 += redL[w * 32 + T2 * 16 + q];
        }
        const float inv = 1.0f / fmaxf(l2, 1e-37f);
        const float inv1 = 1.0f / (1.0f - tt + 1e-10f);
        const float cf = (mh == 0) ? (0.5f * dt * inv1) : (dt * inv1);
        // lane owns (tok=q, d=g*4+j) of its tile: contiguous float4
        float4 xb = *(const float4*)(xT + (T2 * 16 + q) * XSTR + g * 4);
        float4 xs = mh ? *(const float4*)(xM + (T2 * 16 + q) * XSTR + g * 4) : xb;
        float4 xn;
        xn.x = fmaf(cf, m[0] * inv - xs.x, xb.x);
        xn.y = fmaf(cf, m[1] * inv - xs.y, xb.y);
        xn.z = fmaf(cf, m[2] * inv - xs.z, xb.z);
        xn.w = fmaf(cf, m[3] * inv - xs.w, xb.w);
        *(float4*)((mh ? xT : xM) + (T2 * 16 + q) * XSTR + g * 4) = xn;
      }
      __syncthreads();
    }
  }

  // ---- outputs: x_final ----
  if (tid < 128)
    *(float4*)(out + tok0 * 16 + tid * 4) =
        *(const float4*)(xT + (tid >> 2) * XSTR + (tid & 3) * 4);

  // ---- VQ argmin via bf16 MFMA (bit-identical to R10): dist = cc - 2 x.c ----
  union { u32 u[4]; s8v v; } Vx0, Vx1;
#pragma unroll
  for (int T = 0; T < 2; T++) {
    const float* xp = xT + (T * 16 + q) * XSTR + (g & 1) * 8;
    float4 a = *(const float4*)(xp);
    float4 b = *(const float4*)(xp + 4);
    u32 h0 = cvtpk(a.x, a.y), h1 = cvtpk(a.z, a.w);
    u32 h2 = cvtpk(b.x, b.y), h3 = cvtpk(b.z, b.w);
    u32 r0, r1, r2, r3;
    if (g < 2) {
      r0 = h0; r1 = h1; r2 = h2; r3 = h3;
    } else {
      r0 = cvtpk(a.x - lof(h0), a.y - hif(h0));
      r1 = cvtpk(a.z - lof(h1), a.w - hif(h1));
      r2 = cvtpk(b.x - lof(h2), b.y - hif(h2));
      r3 = cvtpk(b.z - lof(h3), b.w - hif(h3));
    }
    if (T == 0) { Vx0.u[0] = r0; Vx0.u[1] = r1; Vx0.u[2] = r2; Vx0.u[3] = r3; }
    else        { Vx1.u[0] = r0; Vx1.u[1] = r1; Vx1.u[2] = r2; Vx1.u[3] = r3; }
  }
  float mv0 = 3.402823466e38f, mv1 = 3.402823466e38f;
  int mi0 = 0, mi1 = 0;
  s8v pAh0, pAl0, pAh1, pAl1;
  s8v qAh0, qAl0, qAh1, qAl1;
  float4 pC0, pC1, qC0, qC1;

#define VQLOAD(P, c) {                                                      \
    const char* _a = ws + WS_VQA + (size_t)(c) * 32768;                     \
    P##Ah0 = *(const s8v*)(_a + s2 * 1024 + lane * 16);                     \
    P##Al0 = *(const s8v*)(_a + 16384 + s2 * 1024 + lane * 16);             \
    P##Ah1 = *(const s8v*)(_a + (s2 + 1) * 1024 + lane * 16);               \
    P##Al1 = *(const s8v*)(_a + 16384 + (s2 + 1) * 1024 + lane * 16);       \
    P##C0 = *(const float4*)(CC2 + (c) * 256 + s2 * 16 + (lane >> 4) * 4);  \
    P##C1 = *(const float4*)(CC2 + (c) * 256 + (s2 + 1) * 16 + (lane >> 4) * 4); \
  }

#define VQMIN(MV, MI, DV, IDX) { float _d = (DV); if (_d < MV) { MV = _d; MI = (IDX); } }

#define VQTILE(P, VX, MV, MI, c) {                                          \
    const int _b0 = (c) * 256 + s2 * 16 + (lane >> 4) * 4;                  \
    const int _b1 = _b0 + 16;                                               \
    f4 _E0 = {P##C0.x, P##C0.y, P##C0.z, P##C0.w};                          \
    _E0 = __builtin_amdgcn_mfma_f32_16x16x32_bf16(P##Ah0, VX, _E0, 0, 0, 0);\
    _E0 = __builtin_amdgcn_mfma_f32_16x16x32_bf16(P##Al0, VX, _E0, 0, 0, 0);\
    f4 _E1 = {P##C1.x, P##C1.y, P##C1.z, P##C1.w};                          \
    _E1 = __builtin_amdgcn_mfma_f32_16x16x32_bf16(P##Ah1, VX, _E1, 0, 0, 0);\
    _E1 = __builtin_amdgcn_mfma_f32_16x16x32_bf16(P##Al1, VX, _E1, 0, 0, 0);\
    VQMIN(MV, MI, _E0[0], _b0 + 0); VQMIN(MV, MI, _E0[1], _b0 + 1);         \
    VQMIN(MV, MI, _E0[2], _b0 + 2); VQMIN(MV, MI, _E0[3], _b0 + 3);         \
    VQMIN(MV, MI, _E1[0], _b1 + 0); VQMIN(MV, MI, _E1[1], _b1 + 1);         \
    VQMIN(MV, MI, _E1[2], _b1 + 2); VQMIN(MV, MI, _E1[3], _b1 + 3);         \
  }

#define VQSTEP(P, c) { VQTILE(P, Vx0.v, mv0, mi0, c) VQTILE(P, Vx1.v, mv1, mi1, c) }

  VQLOAD(p, cpar);
#pragma unroll 1
  for (int i = 0; i < 16; i += 2) {
    VQLOAD(q, cpar + 2 * (i + 1));
    VQSTEP(p, cpar + 2 * i);
    if (i + 2 < 16) VQLOAD(p, cpar + 2 * (i + 2));
    VQSTEP(q, cpar + 2 * (i + 1));
  }
  // cross-lane argmin over the 4 lanes sharing tok = lane&15 (rows)
#pragma unroll
  for (int m = 16; m < 64; m <<= 1) {
    float ov0 = __shfl_xor(mv0, m, 64); int oi0 = __shfl_xor(mi0, m, 64);
    if (ov0 < mv0 || (ov0 == mv0 && oi0 < mi0)) { mv0 = ov0; mi0 = oi0; }
    float ov1 = __shfl_xor(mv1, m, 64); int oi1 = __shfl_xor(mi1, m, 64);
    if (ov1 < mv1 || (ov1 == mv1 && oi1 < mi1)) { mv1 = ov1; mi1 = oi1; }
  }
  if (lane < 16) {
    redV[wave * 32 + lane] = mv0; redI[wave * 32 + lane] = mi0;
    redV[wave * 32 + 16 + lane] = mv1; redI[wave * 32 + 16 + lane] = mi1;
  }
  __syncthreads();
  if (tid < 32) {
    float bv = redV[tid];
    int bi = redI[tid];
#pragma unroll
    for (int w = 1; w < 16; w++) {
      float ov = redV[w * 32 + tid];
      int oi = redI[w * 32 + tid];
      if (ov < bv || (ov == bv && oi < bi)) { bv = ov; bi = oi; }
    }
    out[NTOK * 16 + tok0 + tid] = (float)bi;
  }
}

extern "C" void kernel_launch(void* const* d_in, const int* in_sizes, int n_in,
                              void* d_out, int out_size, void* d_ws, size_t ws_size,
                              hipStream_t stream) {
  const float* x0 = (const float*)d_in[0];
  const float* cb = (const float*)d_in[1];
  const float* Wm = (const float*)d_in[2];
  const float* bm = (const float*)d_in[3];
  const float* tp = (const float*)d_in[4];
  const int* ns = (const int*)d_in[5];
  char* ws = (char*)d_ws;  // needs 1933312 B
  float* out = (float*)d_out;

  prep_kernel<<<512, 64, 0, stream>>>(cb, Wm, bm, tp, ws);
  flow_kernel<<<256, 1024, 0, stream>>>(x0, ws, cb, ns, out);
}

// Round 17
// 239.595 us; speedup vs baseline: 1.0928x; 1.0038x over previous
//
#include <hip/hip_runtime.h>

#define KS 1.8033688011112042f  // log2(e)/0.8
#define ZSH 8.0f                // constant exponent shift: E *= 2^-8 (cancels in mu)
#define NTOK 8192
#define VV 8192
#define CHB 26624               // f16 chunk: W 16K + C 8K + BB 1K + BT 1K
#define WS_CC2B 851968
#define WS_VQA  884736          // (-2C) bf16 hi/lo frags, 32 x 32768 -> ws 1933312 B
#define XSTR 20                 // padded token stride for xT/xM (bank-conflict fix)

typedef float f4 __attribute__((ext_vector_type(4)));
typedef short s8v __attribute__((ext_vector_type(8)));
typedef _Float16 h8v __attribute__((ext_vector_type(8)));
typedef __fp16 fp16v2 __attribute__((ext_vector_type(2)));  // builtin's return type
typedef unsigned int u32;
#define AS1 __attribute__((address_space(1)))
#define AS3 __attribute__((address_space(3)))

// RNE float->bf16, bit-ops (prep + VQ path)
static __device__ __forceinline__ unsigned short f2bf(float f) {
  u32 u = __float_as_uint(f);
  return (unsigned short)((u + 0x7fffu + ((u >> 16) & 1u)) >> 16);
}
static __device__ __forceinline__ unsigned short f2h(float f) {  // RNE f32->f16
  _Float16 h = (_Float16)f;
  return __builtin_bit_cast(unsigned short, h);
}
// f16 pack via PLAIN CASTS (RNE; used on the cold x-packing path)
static __device__ __forceinline__ u32 pkh(float a, float b) {
  return (u32)f2h(a) | ((u32)f2h(b) << 16);
}
static __device__ __forceinline__ float h2f(float a) {  // RNE f16 of a, as f32
  return (float)(_Float16)a;
}
// official builtin packed RTZ f16 conversion (hot E-packing path)
static __device__ __forceinline__ u32 pkrtz_b(float a, float b) {
  fp16v2 r = __builtin_amdgcn_cvt_pkrtz(a, b);
  return __builtin_bit_cast(u32, r);
}
// bf16 pack for the VQ path (proven since R3)
static __device__ __forceinline__ u32 cvtpk(float a, float b) {
  u32 r;
  asm("v_cvt_pk_bf16_f32 %0, %1, %2" : "=v"(r) : "v"(a), "v"(b));
  return r;
}
static __device__ __forceinline__ float lof(u32 h) {  // low bf16 as f32
  return __uint_as_float(h << 16);
}
static __device__ __forceinline__ float hif(u32 h) {  // high bf16 as f32
  return __uint_as_float(h & 0xffff0000u);
}

// ws layout (f16 flow path): 32 chunks x 26624 B:
//   [0,16384)     Wf16: 16 subtiles x 64 lanes x 8 f16 (A of mfma1, W*KS, RNE)
//   [16384,24576) Cf16: 8 PAIRS x 64 lanes x 8 f16 (A of mfma2, K=32 pairing)
//   [24576,25600) BB fp32[256] (bm*KS - 8)   [25600,26624) BT fp32[256]
// CC2 fp32[8192] at WS_CC2B; VQA ((-2C) bf16 hi/lo, mfma1-A layout) at WS_VQA.
// R17: prep consolidated 512x64 -> 64x512 (8 waves/block, wave w = subtile
// blockIdx*8+w; per-lane code identical, outputs bit-identical). The 512
// single-wave launches were ~25-35 us of the wall (flow dispatch ~195 vs
// wall 240); this is pure dispatch-overhead removal.
__global__ __launch_bounds__(512) void prep_kernel(
    const float* __restrict__ cb, const float* __restrict__ Wm,
    const float* __restrict__ bm, const float* __restrict__ tp,
    char* __restrict__ ws) {
  const int ct = blockIdx.x * 8 + (threadIdx.x >> 6);  // subtile 0..511
  const int l = threadIdx.x & 63;
  const int g = l >> 4, q = l & 15;
  const int c = ct >> 4, p = ct & 15;
  const int s = p >> 1, par = p & 1;
  char* chunk = ws + (size_t)c * CHB;
  {  // W fragment (A of mfma1): row=code=ct*16+q, k=g*8+j, d=k&15, f16 RNE
    const int code = ct * 16 + q;
    unsigned short wh[8];
#pragma unroll
    for (int j = 0; j < 8; j++) {
      int d = (g * 8 + j) & 15;
      wh[j] = f2h(Wm[d * VV + code] * KS);
    }
    uint4 hv;
    hv.x = (u32)wh[0] | ((u32)wh[1] << 16); hv.y = (u32)wh[2] | ((u32)wh[3] << 16);
    hv.z = (u32)wh[4] | ((u32)wh[5] << 16); hv.w = (u32)wh[6] | ((u32)wh[7] << 16);
    *(uint4*)(chunk + p * 1024 + l * 16) = hv;
  }
  {  // VQ A-fragment: (-2*C) bf16 hi/lo in mfma1-A layout (unchanged, proven)
    const int code = ct * 16 + q;
    unsigned short vh[8], vo[8];
#pragma unroll
    for (int j = 0; j < 8; j++) {
      int d = (g * 8 + j) & 15;
      float v = -2.0f * cb[code * 16 + d];
      unsigned short h = f2bf(v);
      vh[j] = h;
      vo[j] = f2bf(v - __uint_as_float((u32)h << 16));
    }
    uint4 hv, lv;
    hv.x = (u32)vh[0] | ((u32)vh[1] << 16); hv.y = (u32)vh[2] | ((u32)vh[3] << 16);
    hv.z = (u32)vh[4] | ((u32)vh[5] << 16); hv.w = (u32)vh[6] | ((u32)vh[7] << 16);
    lv.x = (u32)vo[0] | ((u32)vo[1] << 16); lv.y = (u32)vo[2] | ((u32)vo[3] << 16);
    lv.z = (u32)vo[4] | ((u32)vo[5] << 16); lv.w = (u32)vo[6] | ((u32)vo[7] << 16);
    char* vq = ws + WS_VQA + (size_t)c * 32768;
    *(uint4*)(vq + p * 1024 + l * 16) = hv;
    *(uint4*)(vq + 16384 + p * 1024 + l * 16) = lv;
  }
  {  // C pair-fragment (A of mfma2), f16 RNE: elems par*4+{0..3} of pair s
    unsigned short ch[4];
#pragma unroll
    for (int j = 0; j < 4; j++) {
      int code = ct * 16 + g * 4 + j;
      ch[j] = f2h(cb[code * 16 + q]);
    }
    uint2 hv = make_uint2((u32)ch[0] | ((u32)ch[1] << 16),
                          (u32)ch[2] | ((u32)ch[3] << 16));
    *(uint2*)(chunk + 16384 + s * 1024 + l * 16 + par * 8) = hv;
  }
  if (l < 16) {
    const int code = ct * 16 + l;
    *(float*)(chunk + 24576 + p * 64 + l * 4) = bm[code] * KS - ZSH;
    *(float*)(chunk + 25600 + p * 64 + l * 4) = tp[code] * KS;
    float ss = 0.f;
#pragma unroll
    for (int d = 0; d < 16; d++) { float v = cb[code * 16 + d]; ss = fmaf(v, v, ss); }
    *(float*)(ws + WS_CC2B + code * 4) = ss;
  }
}

// Flow kernel: UNCHANGED from R16 (proven best: 195 us, 90% combined issue,
// conflicts 2M, absmax 1.22e-4). R15's lesson: don't gamble the hot loop.
__global__ __launch_bounds__(1024, 4) void flow_kernel(
    const float* __restrict__ x0, const char* __restrict__ ws,
    const float* __restrict__ cb, const int* __restrict__ nsp,
    float* __restrict__ out) {
  __shared__ __align__(16) char smem[142336];
  char* biasL = smem;                       // [32 chunks][2048 B] BB|BT
  float* xT = (float*)(smem + 65536);       // [32][XSTR] base state (2560 B)
  float* xM = (float*)(smem + 68096);       // [32][XSTR] midpoint state
  char* redMp = smem + 70656;               // [16 waves][2 tiles][64] f4 (32 KB)
  float* redL = (float*)(smem + 103424);    // [16][32] lsum partials
  float* redV = (float*)(smem + 105472);    // [16][32] VQ min val
  int* redI = (int*)(smem + 107520);        // [16][32] VQ min idx
  float* zL = (float*)(smem + 109568);      // [32 chunks][256] z table (32 KB)
  const float* CC2 = (const float*)(ws + WS_CC2B);

  const int tid = threadIdx.x;
  const int lane = tid & 63, wave = tid >> 6;  // 16 waves
  const int s = wave & 7, cpar = wave >> 3;    // pair id, chunk parity
  const int s2 = s * 2;
  const int g = lane >> 4, q = lane & 15;
  const int tok0 = blockIdx.x * 32;

  if (tid < 128)
    *(float4*)(xT + (tid >> 2) * XSTR + (tid & 3) * 4) =
        *(const float4*)(x0 + tok0 * 16 + tid * 4);
  // biases -> LDS once (wave-uniform dst base + lane*16: valid global_load_lds)
#pragma unroll
  for (int sw = 0; sw < 4; sw++) {
    const int c = sw * 8 + (tid >> 7);
    const int off = (tid & 127) * 16;
    __builtin_amdgcn_global_load_lds(
        (const AS1 u32*)(ws + (size_t)c * CHB + 24576 + off),
        (AS3 u32*)(biasL + c * 2048 + off), 16, 0, 0);
  }
  __syncthreads();

  const int n_steps = *nsp;
  const float dt = 1.0f / (float)(n_steps - 1);

  // ones A-fragment (f16 1.0 pairs) for the lsum MFMA
  union { u32 u[4]; h8v h; } ONESH;
  ONESH.u[0] = ONESH.u[1] = ONESH.u[2] = ONESH.u[3] = 0x3c003c00u;

  // named double-buffered fragment registers (NO arrays — rule #20)
  h8v aW0, aW1, aCf;
  h8v bW0, bW1, bCf;

// conflict-light ZFILL: lanes write 16-B-contiguous (2 passes of 128 floats)
#define ZFILL(TT) {                                                         \
    const int _c = tid >> 5;                                                \
    const int _t = tid & 31;                                                \
    const char* _bp = biasL + _c * 2048;                                    \
    float4 _b0 = *(const float4*)(_bp + _t * 16);                           \
    float4 _t0 = *(const float4*)(_bp + 1024 + _t * 16);                    \
    float4 _b1 = *(const float4*)(_bp + 512 + _t * 16);                     \
    float4 _t1 = *(const float4*)(_bp + 1536 + _t * 16);                    \
    float4 _za, _zb;                                                        \
    _za.x = fmaf(TT, _t0.x, _b0.x); _za.y = fmaf(TT, _t0.y, _b0.y);         \
    _za.z = fmaf(TT, _t0.z, _b0.z); _za.w = fmaf(TT, _t0.w, _b0.w);         \
    _zb.x = fmaf(TT, _t1.x, _b1.x); _zb.y = fmaf(TT, _t1.y, _b1.y);         \
    _zb.z = fmaf(TT, _t1.z, _b1.z); _zb.w = fmaf(TT, _t1.w, _b1.w);         \
    *(float4*)(zL + _c * 256 + _t * 4) = _za;                               \
    *(float4*)(zL + _c * 256 + 128 + _t * 4) = _zb;                         \
  }

#define LOADF(P, c) {                                                       \
    const char* _p = ws + (size_t)(c) * CHB;                                \
    P##W0 = *(const h8v*)(_p + s2 * 1024 + lane * 16);                      \
    P##W1 = *(const h8v*)(_p + (s2 + 1) * 1024 + lane * 16);                \
    P##Cf = *(const h8v*)(_p + 16384 + s * 1024 + lane * 16);               \
  }

#define TBODY(W0F, W1F, CFF, BX, MACC, LACC, Z0, Z1) {                      \
    f4 _D0 = {Z0.x, Z0.y, Z0.z, Z0.w};  /* bias (incl -8 shift) as C-in */  \
    _D0 = __builtin_amdgcn_mfma_f32_16x16x32_f16(W0F, BX, _D0, 0, 0, 0);    \
    f4 _D1 = {Z1.x, Z1.y, Z1.z, Z1.w};                                      \
    _D1 = __builtin_amdgcn_mfma_f32_16x16x32_f16(W1F, BX, _D1, 0, 0, 0);    \
    float _e0 = __builtin_amdgcn_exp2f(_D0[0]);                             \
    float _e1 = __builtin_amdgcn_exp2f(_D0[1]);                             \
    float _e2 = __builtin_amdgcn_exp2f(_D0[2]);                             \
    float _e3 = __builtin_amdgcn_exp2f(_D0[3]);                             \
    float _e4 = __builtin_amdgcn_exp2f(_D1[0]);                             \
    float _e5 = __builtin_amdgcn_exp2f(_D1[1]);                             \
    float _e6 = __builtin_amdgcn_exp2f(_D1[2]);                             \
    float _e7 = __builtin_amdgcn_exp2f(_D1[3]);                             \
    union { u32 u[4]; h8v h; } _Eh;                                         \
    _Eh.u[0] = pkrtz_b(_e0, _e1); _Eh.u[1] = pkrtz_b(_e2, _e3);             \
    _Eh.u[2] = pkrtz_b(_e4, _e5); _Eh.u[3] = pkrtz_b(_e6, _e7);             \
    MACC = __builtin_amdgcn_mfma_f32_16x16x32_f16(CFF, _Eh.h, MACC, 0, 0, 0); \
    LACC = __builtin_amdgcn_mfma_f32_16x16x32_f16(ONESH.h, _Eh.h, LACC, 0, 0, 0); \
  }

#define COMPUTE(P, c) {                                                     \
    const float* _zp = zL + (c) * 256 + s2 * 16 + g * 4;                    \
    float4 _z0 = *(const float4*)(_zp);                                     \
    float4 _z1 = *(const float4*)(_zp + 16);                                \
    TBODY(P##W0, P##W1, P##Cf, Bx0.h, macc0, lacc0, _z0, _z1);              \
    TBODY(P##W0, P##W1, P##Cf, Bx1.h, macc1, lacc1, _z0, _z1);              \
  }

  // prologue: z table for phase 0 (tt = 0) + first chunk prefetch
  ZFILL(0.0f);
  LOADF(a, cpar);
  __syncthreads();

  for (int step = 0; step < n_steps - 1; step++) {
#pragma unroll 1
    for (int mh = 0; mh < 2; mh++) {
      const float tt = (float)step * dt + (mh ? 0.5f * dt : 0.0f);
      const float* xsrc = mh ? xM : xT;
      // B-frags of mfma1: col=tok=q, k=g*8+j; k<16 -> xh[d=k] (f16 RNE),
      // k>=16 -> xl[d=k-16] (residual vs the same RNE). g covers d=(g&1)*8..+7.
      union { u32 u[4]; h8v h; } Bx0, Bx1;
#pragma unroll
      for (int T = 0; T < 2; T++) {
        const float* xp = xsrc + (T * 16 + q) * XSTR + (g & 1) * 8;
        float4 a = *(const float4*)(xp);
        float4 b = *(const float4*)(xp + 4);
        u32 r0, r1, r2, r3;
        if (g < 2) {
          r0 = pkh(a.x, a.y); r1 = pkh(a.z, a.w);
          r2 = pkh(b.x, b.y); r3 = pkh(b.z, b.w);
        } else {
          r0 = pkh(a.x - h2f(a.x), a.y - h2f(a.y));
          r1 = pkh(a.z - h2f(a.z), a.w - h2f(a.w));
          r2 = pkh(b.x - h2f(b.x), b.y - h2f(b.y));
          r3 = pkh(b.z - h2f(b.z), b.w - h2f(b.w));
        }
        if (T == 0) { Bx0.u[0] = r0; Bx0.u[1] = r1; Bx0.u[2] = r2; Bx0.u[3] = r3; }
        else        { Bx1.u[0] = r0; Bx1.u[1] = r1; Bx1.u[2] = r2; Bx1.u[3] = r3; }
      }
      f4 macc0 = {0.f, 0.f, 0.f, 0.f}, macc1 = {0.f, 0.f, 0.f, 0.f};
      f4 lacc0 = {0.f, 0.f, 0.f, 0.f}, lacc1 = {0.f, 0.f, 0.f, 0.f};

      // chunk pipeline: this wave's 16 chunks {cpar, cpar+2, ...}, 1 ahead
      // (a-regs preloaded with chunk cpar by prologue / previous phase tail)
#pragma unroll 1
      for (int j = 0; j < 16; j += 2) {
        LOADF(b, cpar + 2 * (j + 1));
        COMPUTE(a, cpar + 2 * j);
        if (j + 2 < 16) LOADF(a, cpar + 2 * (j + 2));
        COMPUTE(b, cpar + 2 * (j + 1));
      }

      // partials: macc per lane; lsum complete per tok in lacc (any row reg)
      *(f4*)(redMp + ((wave * 2 + 0) * 64 + lane) * 16) = macc0;
      *(f4*)(redMp + ((wave * 2 + 1) * 64 + lane) * 16) = macc1;
      if (lane < 16) {
        redL[wave * 32 + lane] = lacc0[0];
        redL[wave * 32 + 16 + lane] = lacc1[0];
      }
      __syncthreads();
      // prefetch next phase's first chunk — L2 latency hides under finalize
      LOADF(a, cpar);
      // z table for the NEXT phase — overlaps the finalize serial window
      const float ttn = (mh == 0) ? (tt + 0.5f * dt) : ((float)(step + 1) * dt);
      ZFILL(ttn);
      if ((wave & 7) == 0) {  // waves 0 (tile0) and 8 (tile1) finalize
        const int T2 = wave >> 3;
        f4 m = {0.f, 0.f, 0.f, 0.f};
        float l2 = 0.f;
#pragma unroll
        for (int w = 0; w < 16; w++) {
          f4 o = *(const f4*)(redMp + ((w * 2 + T2) * 64 + lane) * 16);
          m += o;
          l2 += redL[w * 32 + T2 * 16 + q];
        }
        const float inv = 1.0f / fmaxf(l2, 1e-37f);
        const float inv1 = 1.0f / (1.0f - tt + 1e-10f);
        const float cf = (mh == 0) ? (0.5f * dt * inv1) : (dt * inv1);
        // lane owns (tok=q, d=g*4+j) of its tile: contiguous float4
        float4 xb = *(const float4*)(xT + (T2 * 16 + q) * XSTR + g * 4);
        float4 xs = mh ? *(const float4*)(xM + (T2 * 16 + q) * XSTR + g * 4) : xb;
        float4 xn;
        xn.x = fmaf(cf, m[0] * inv - xs.x, xb.x);
        xn.y = fmaf(cf, m[1] * inv - xs.y, xb.y);
        xn.z = fmaf(cf, m[2] * inv - xs.z, xb.z);
        xn.w = fmaf(cf, m[3] * inv - xs.w, xb.w);
        *(float4*)((mh ? xT : xM) + (T2 * 16 + q) * XSTR + g * 4) = xn;
      }
      __syncthreads();
    }
  }

  // ---- outputs: x_final ----
  if (tid < 128)
    *(float4*)(out + tok0 * 16 + tid * 4) =
        *(const float4*)(xT + (tid >> 2) * XSTR + (tid & 3) * 4);

  // ---- VQ argmin via bf16 MFMA (bit-identical to R10): dist = cc - 2 x.c ----
  union { u32 u[4]; s8v v; } Vx0, Vx1;
#pragma unroll
  for (int T = 0; T < 2; T++) {
    const float* xp = xT + (T * 16 + q) * XSTR + (g & 1) * 8;
    float4 a = *(const float4*)(xp);
    float4 b = *(const float4*)(xp + 4);
    u32 h0 = cvtpk(a.x, a.y), h1 = cvtpk(a.z, a.w);
    u32 h2 = cvtpk(b.x, b.y), h3 = cvtpk(b.z, b.w);
    u32 r0, r1, r2, r3;
    if (g < 2) {
      r0 = h0; r1 = h1; r2 = h2; r3 = h3;
    } else {
      r0 = cvtpk(a.x - lof(h0), a.y - hif(h0));
      r1 = cvtpk(a.z - lof(h1), a.w - hif(h1));
      r2 = cvtpk(b.x - lof(h2), b.y - hif(h2));
      r3 = cvtpk(b.z - lof(h3), b.w - hif(h3));
    }
    if (T == 0) { Vx0.u[0] = r0; Vx0.u[1] = r1; Vx0.u[2] = r2; Vx0.u[3] = r3; }
    else        { Vx1.u[0] = r0; Vx1.u[1] = r1; Vx1.u[2] = r2; Vx1.u[3] = r3; }
  }
  float mv0 = 3.402823466e38f, mv1 = 3.402823466e38f;
  int mi0 = 0, mi1 = 0;
  s8v pAh0, pAl0, pAh1, pAl1;
  s8v qAh0, qAl0, qAh1, qAl1;
  float4 pC0, pC1, qC0, qC1;

#define VQLOAD(P, c) {                                                      \
    const char* _a = ws + WS_VQA + (size_t)(c) * 32768;                     \
    P##Ah0 = *(const s8v*)(_a + s2 * 1024 + lane * 16);                     \
    P##Al0 = *(const s8v*)(_a + 16384 + s2 * 1024 + lane * 16);             \
    P##Ah1 = *(const s8v*)(_a + (s2 + 1) * 1024 + lane * 16);               \
    P##Al1 = *(const s8v*)(_a + 16384 + (s2 + 1) * 1024 + lane * 16);       \
    P##C0 = *(const float4*)(CC2 + (c) * 256 + s2 * 16 + (lane >> 4) * 4);  \
    P##C1 = *(const float4*)(CC2 + (c) * 256 + (s2 + 1) * 16 + (lane >> 4) * 4); \
  }

#define VQMIN(MV, MI, DV, IDX) { float _d = (DV); if (_d < MV) { MV = _d; MI = (IDX); } }

#define VQTILE(P, VX, MV, MI, c) {                                          \
    const int _b0 = (c) * 256 + s2 * 16 + (lane >> 4) * 4;                  \
    const int _b1 = _b0 + 16;                                               \
    f4 _E0 = {P##C0.x, P##C0.y, P##C0.z, P##C0.w};                          \
    _E0 = __builtin_amdgcn_mfma_f32_16x16x32_bf16(P##Ah0, VX, _E0, 0, 0, 0);\
    _E0 = __builtin_amdgcn_mfma_f32_16x16x32_bf16(P##Al0, VX, _E0, 0, 0, 0);\
    f4 _E1 = {P##C1.x, P##C1.y, P##C1.z, P##C1.w};                          \
    _E1 = __builtin_amdgcn_mfma_f32_16x16x32_bf16(P##Ah1, VX, _E1, 0, 0, 0);\
    _E1 = __builtin_amdgcn_mfma_f32_16x16x32_bf16(P##Al1, VX, _E1, 0, 0, 0);\
    VQMIN(MV, MI, _E0[0], _b0 + 0); VQMIN(MV, MI, _E0[1], _b0 + 1);         \
    VQMIN(MV, MI, _E0[2], _b0 + 2); VQMIN(MV, MI, _E0[3], _b0 + 3);         \
    VQMIN(MV, MI, _E1[0], _b1 + 0); VQMIN(MV, MI, _E1[1], _b1 + 1);         \
    VQMIN(MV, MI, _E1[2], _b1 + 2); VQMIN(MV, MI, _E1[3], _b1 + 3);         \
  }

#define VQSTEP(P, c) { VQTILE(P, Vx0.v, mv0, mi0, c) VQTILE(P, Vx1.v, mv1, mi1, c) }

  VQLOAD(p, cpar);
#pragma unroll 1
  for (int i = 0; i < 16; i += 2) {
    VQLOAD(q, cpar + 2 * (i + 1));
    VQSTEP(p, cpar + 2 * i);
    if (i + 2 < 16) VQLOAD(p, cpar + 2 * (i + 2));
    VQSTEP(q, cpar + 2 * (i + 1));
  }
  // cross-lane argmin over the 4 lanes sharing tok = lane&15 (rows)
#pragma unroll
  for (int m = 16; m < 64; m <<= 1) {
    float ov0 = __shfl_xor(mv0, m, 64); int oi0 = __shfl_xor(mi0, m, 64);
    if (ov0 < mv0 || (ov0 == mv0 && oi0 < mi0)) { mv0 = ov0; mi0 = oi0; }
    float ov1 = __shfl_xor(mv1, m, 64); int oi1 = __shfl_xor(mi1, m, 64);
    if (ov1 < mv1 || (ov1 == mv1 && oi1 < mi1)) { mv1 = ov1; mi1 = oi1; }
  }
  if (lane < 16) {
    redV[wave * 32 + lane] = mv0; redI[wave * 32 + lane] = mi0;
    redV[wave * 32 + 16 + lane] = mv1; redI[wave * 32 + 16 + lane] = mi1;
  }
  __syncthreads();
  if (tid < 32) {
    float bv = redV[tid];
    int bi = redI[tid];
#pragma unroll
    for (int w = 1; w < 16; w++) {
      float ov = redV[w * 32 + tid];
      int oi = redI[w * 32 + tid];
      if (ov < bv || (ov == bv && oi < bi)) { bv = ov; bi = oi; }
    }
    out[NTOK * 16 + tok0 + tid] = (float)bi;
  }
}

extern "C" void kernel_launch(void* const* d_in, const int* in_sizes, int n_in,
                              void* d_out, int out_size, void* d_ws, size_t ws_size,
                              hipStream_t stream) {
  const float* x0 = (const float*)d_in[0];
  const float* cb = (const float*)d_in[1];
  const float* Wm = (const float*)d_in[2];
  const float* bm = (const float*)d_in[3];
  const float* tp = (const float*)d_in[4];
  const int* ns = (const int*)d_in[5];
  char* ws = (char*)d_ws;  // needs 1933312 B
  float* out = (float*)d_out;

  prep_kernel<<<64, 512, 0, stream>>>(cb, Wm, bm, tp, ws);
  flow_kernel<<<256, 1024, 0, stream>>>(x0, ws, cb, ns, out);
}